// Round 2
// baseline (214.852 us; speedup 1.0000x reference)
//
#include <hip/hip_runtime.h>
#include <hip/hip_bf16.h>
#include <stdint.h>

// Problem constants (all inputs & output are FP32 per the reference file)
#define BATCH 128
#define LAT   2000
#define NG    10000
#define KW    20
#define OUTW  (NG * KW)   // 200000
#define EPSV  1e-5f

// ---- Phase 1 (GEMM) tiling: block tile = 64 groups x 128 batch
// split-K=8: klen 256 x7 + 208, 157*8 = 1256 blocks -> 4 blocks/CU resident
#define GT    64
#define BK    64
#define KSPL  8
#define KSEG  256           // kbase = s*KSEG; last split klen = 2000-7*256 = 208
#define NKT   32            // 64-wide k-tiles in padded z (2048 = 32*64)

// ---- Phase 2 (fused BN-stats + expand): groups per block
#define EG        16
#define HR_STRIDE 132   // LDS row stride (floats): 132%32=4 -> <=2-way bank alias (free)

typedef __bf16 bf16x8 __attribute__((ext_vector_type(8)));
typedef float  f32x4  __attribute__((ext_vector_type(4)));

__device__ __forceinline__ ushort f2bf(float f) {
  uint32_t u = __builtin_bit_cast(uint32_t, f);
  u = (u + 0x7FFFu + ((u >> 16) & 1u)) >> 16;  // RNE
  return (ushort)u;
}

__device__ __forceinline__ int4 pack8(const float* p) {
  float4 f0 = *(const float4*)p;
  float4 f1 = *(const float4*)(p + 4);
  int4 v;
  v.x = (int)((uint32_t)f2bf(f0.x) | ((uint32_t)f2bf(f0.y) << 16));
  v.y = (int)((uint32_t)f2bf(f0.z) | ((uint32_t)f2bf(f0.w) << 16));
  v.z = (int)((uint32_t)f2bf(f1.x) | ((uint32_t)f2bf(f1.y) << 16));
  v.w = (int)((uint32_t)f2bf(f1.z) | ((uint32_t)f2bf(f1.w) << 16));
  return v;
}

// async 16B global -> LDS (linear dest = wave-uniform base + lane*16)
__device__ __forceinline__ void gload_lds16(const void* g, void* l) {
  __builtin_amdgcn_global_load_lds(
      (const __attribute__((address_space(1))) unsigned int*)g,
      (__attribute__((address_space(3))) unsigned int*)l, 16, 0, 0);
}

// =====================================================================
// Phase 0: z (128 x 2000 f32) -> bf16, zero-padded to K=2048, stored in
// the EXACT swizzled-LDS image order per 64-k-tile so the GEMM can stage
// it with plain 16B global_load_lds (linear dest + pre-swizzled source).
// Image: chunk c (16B) of tile kt: r=c>>3, j=c&7 holds z[r][kt*64+(j^(r&7))*8 ..+8].
// =====================================================================
__global__ __launch_bounds__(256) void zprep_kernel(
    const float* __restrict__ zp, int4* __restrict__ zswz) {
  const int kt  = blockIdx.x;          // 0..31
  const int tid = threadIdx.x;
#pragma unroll
  for (int i = 0; i < 4; ++i) {
    int c = i * 256 + tid;             // 0..1023
    int r = c >> 3, j = c & 7;
    int sc = j ^ (r & 7);
    int k0 = kt * 64 + sc * 8;
    int4 v = make_int4(0, 0, 0, 0);
    if (k0 < LAT) v = pack8(zp + (size_t)r * LAT + k0);   // LAT%8==0: no straddle
    zswz[(size_t)kt * 1024 + c] = v;
  }
}

// =====================================================================
// Phase 1: split-K GEMM  hp[s][g][b] = sum_{k in split s} W[g,k] * z[b,k]
// A-operand = W rows (m=group), B-operand = z rows (n=batch) so the MFMA
// D layout (row=q*4+reg=group, col=lane&15=batch) gives b-contiguous stores.
// b_fc skipped: cancels under training-mode batchnorm.
// z tile staged via global_load_lds from the pre-swizzled bf16 image (no
// VALU, no VGPRs); W tile packed f32->bf16 in-flight (read-once, optimal).
// =====================================================================
__global__ __launch_bounds__(256, 4) void gemm_splitk_kernel(
    const int4* __restrict__ zswz, const float* __restrict__ wp,
    float* __restrict__ hp) {
  const int tid = threadIdx.x;
  const int g0  = blockIdx.x * GT;
  const int s   = blockIdx.y;               // k-split id
  const int kbase = s * KSEG;
  const int klen  = (s < KSPL - 1) ? KSEG : (LAT - (KSPL - 1) * KSEG);  // 208 last

  // LDS tiles, row stride 64 bf16 (128 B), 16B-chunk XOR-by-row swizzle.
  __shared__ __attribute__((aligned(16))) ushort As[GT * BK];     //  8 KB (W)
  __shared__ __attribute__((aligned(16))) ushort Bs[BATCH * BK];  // 16 KB (z)

  const int lane = tid & 63;
  const int w    = tid >> 6;
  const int wm   = w & 1;      // group half: +wm*32
  const int wn   = w >> 1;     // batch half: +wn*64
  const int q    = lane >> 4;
  const int cl   = lane & 15;

  f32x4 acc[2][4];
  const f32x4 vzero = {0.f, 0.f, 0.f, 0.f};
#pragma unroll
  for (int i = 0; i < 2; ++i)
#pragma unroll
    for (int j = 0; j < 4; ++j) acc[i][j] = vzero;

  for (int it = 0; it < KSEG / BK; ++it) {   // 4 iters
    const int k0 = it * BK;
    __syncthreads();

    // ---- stage B (z tile) first: 4 async 16B copies, latency overlapped
    // by the A-pack VALU below. Source is pre-swizzled; dest linear. ----
    const int4* zt = zswz + (size_t)(s * (KSEG / BK) + it) * 1024;
#pragma unroll
    for (int i = 0; i < 4; ++i) {
      int c = i * 256 + tid;
      gload_lds16(zt + c, &Bs[c * 8]);
    }

    // ---- stage A (W tile): 64 rows x 8 chunks = 512 chunks, 2/thread ----
#pragma unroll
    for (int i = 0; i < 2; ++i) {
      int c = i * 256 + tid;
      int r = c >> 3, sc = c & 7;
      int lk = k0 + sc * 8;
      int g  = g0 + r;
      int4 v = make_int4(0, 0, 0, 0);
      if (lk < klen && g < NG)
        v = pack8(wp + (size_t)g * LAT + kbase + lk);
      *(int4*)&As[r * BK + ((sc ^ (r & 7)) << 3)] = v;
    }
    __syncthreads();

#pragma unroll
    for (int kk = 0; kk < 2; ++kk) {
      int sc = kk * 4 + q;
      bf16x8 af[2], bfr[4];
#pragma unroll
      for (int mt = 0; mt < 2; ++mt) {
        int ra = wm * 32 + mt * 16 + cl;
        af[mt] = *(const bf16x8*)&As[ra * BK + ((sc ^ (ra & 7)) << 3)];
      }
#pragma unroll
      for (int nt = 0; nt < 4; ++nt) {
        int rb = wn * 64 + nt * 16 + cl;
        bfr[nt] = *(const bf16x8*)&Bs[rb * BK + ((sc ^ (rb & 7)) << 3)];
      }
#pragma unroll
      for (int mt = 0; mt < 2; ++mt)
#pragma unroll
        for (int nt = 0; nt < 4; ++nt)
          acc[mt][nt] = __builtin_amdgcn_mfma_f32_16x16x32_bf16(
              af[mt], bfr[nt], acc[mt][nt], 0, 0, 0);
    }
  }

  // ---- store partial h^T: hp[s][g][b], b contiguous ----
  float* base = hp + (size_t)s * NG * BATCH;
#pragma unroll
  for (int mt = 0; mt < 2; ++mt) {
#pragma unroll
    for (int r = 0; r < 4; ++r) {
      int g = g0 + wm * 32 + mt * 16 + q * 4 + r;
      if (g < NG) {
#pragma unroll
        for (int nt = 0; nt < 4; ++nt) {
          int b = wn * 64 + nt * 16 + cl;
          base[(size_t)g * BATCH + b] = acc[mt][nt][r];
        }
      }
    }
  }
}

// =====================================================================
// Phase 2 (fused): per-block 16-group window x all 128 batches.
//  (a) read hp slice ONCE (float4-coalesced), sum 8 k-splits, stash raw h
//      in LDS, BN stats via 32-lane shuffle reduce -> scale/shift in LDS.
//  (b) expansion remapped for store coalescing: tid%80 = fixed float4
//      column of the 1280-B output window, rows walk down batch. A wave's
//      store = 1024 contiguous bytes.
// =====================================================================
__global__ __launch_bounds__(256, 4) void bn_expand_kernel(
    const float* __restrict__ hp, const float* __restrict__ gammap,
    const float* __restrict__ betap, const float* __restrict__ convwp,
    const float* __restrict__ convbp, float* __restrict__ out) {
  const int tid = threadIdx.x;
  const int g0  = blockIdx.x * EG;

  __shared__ float  h_raw[EG * HR_STRIDE];   // raw (pre-BN) h, padded rows
  __shared__ float4 cw_s[EG * 5];            // conv_w window, flat float4
  __shared__ float  cb_s[EG];
  __shared__ float  scale_s[EG];
  __shared__ float  shift_s[EG];

  if (tid < EG * 5)
    cw_s[tid] = *(const float4*)(convwp + (size_t)g0 * KW + tid * 4);
  if (tid < EG) cb_s[tid] = convbp[g0 + tid];

  // ---- (a) load hp slice, split-sum, stash, partial stats ----
  float sm[2], sq[2];
#pragma unroll
  for (int half = 0; half < 2; ++half) {
    const int idx = tid + half * 256;        // 0..511
    const int gl  = idx >> 5;                // local group 0..15
    const int bb  = (idx & 31) * 4;          // batch base 0..124
    float4 a = make_float4(0.f, 0.f, 0.f, 0.f);
#pragma unroll
    for (int s = 0; s < KSPL; ++s) {
      const float4 v =
          *(const float4*)(hp + ((size_t)s * NG + g0 + gl) * BATCH + bb);
      a.x += v.x; a.y += v.y; a.z += v.z; a.w += v.w;
    }
    *(float4*)&h_raw[gl * HR_STRIDE + bb] = a;   // 16B-aligned (132*4=528)
    sm[half] = a.x + a.y + a.z + a.w;
    sq[half] = a.x * a.x + a.y * a.y + a.z * a.z + a.w * a.w;
  }
  // 32 consecutive lanes share one group (aligned) -> masks stay in-group
#pragma unroll
  for (int m = 1; m < 32; m <<= 1) {
    sm[0] += __shfl_xor(sm[0], m); sq[0] += __shfl_xor(sq[0], m);
    sm[1] += __shfl_xor(sm[1], m); sq[1] += __shfl_xor(sq[1], m);
  }
  if ((tid & 31) == 0) {
#pragma unroll
    for (int half = 0; half < 2; ++half) {
      const int gl = (tid >> 5) + half * 8;
      float mean = sm[half] * (1.f / 128.f);
      float var  = sq[half] * (1.f / 128.f) - mean * mean;
      var = (var < 0.f) ? 0.f : var;
      float inv   = __builtin_amdgcn_rsqf(var + EPSV);
      float scale = inv * gammap[g0 + gl];
      scale_s[gl] = scale;
      shift_s[gl] = betap[g0 + gl] - mean * scale;
    }
  }
  __syncthreads();

  // ---- (b) expansion: 240 threads = 3 batch rows x 80 float4 columns ----
  if (tid < 240) {
    const int col4 = tid % 80;           // float4 column in 1280-B window row
    const int r0   = tid / 80;           // 0..2
    const int gl   = col4 / 5;           // local group of this column
    const float4 w4  = cw_s[col4];
    const float  cb  = cb_s[gl];
    const float  scl = scale_s[gl];
    const float  sft = shift_s[gl];
    const float* hsrc = &h_raw[gl * HR_STRIDE];
    float* obase = out + (size_t)g0 * KW + (size_t)col4 * 4;
    for (int j = 0; j < 43; ++j) {       // ceil(128/3) passes
      const int row = j * 3 + r0;        // batch index
      if (row < BATCH) {
        float h = hsrc[row];             // <=2-way LDS bank alias (free)
        h = fmaf(h, scl, sft);
        h = fmaxf(h, h * 0.1f);          // leaky(0.1)
        float y0 = fmaf(h, w4.x, cb);
        float y1 = fmaf(h, w4.y, cb);
        float y2 = fmaf(h, w4.z, cb);
        float y3 = fmaf(h, w4.w, cb);
        y0 = fmaxf(y0, y0 * 0.1f);
        y1 = fmaxf(y1, y1 * 0.1f);
        y2 = fmaxf(y2, y2 * 0.1f);
        y3 = fmaxf(y3, y3 * 0.1f);
        float4 ov;
        ov.x = __builtin_amdgcn_rcpf(1.f + exp2f(y0 * -1.44269504f));
        ov.y = __builtin_amdgcn_rcpf(1.f + exp2f(y1 * -1.44269504f));
        ov.z = __builtin_amdgcn_rcpf(1.f + exp2f(y2 * -1.44269504f));
        ov.w = __builtin_amdgcn_rcpf(1.f + exp2f(y3 * -1.44269504f));
        *(float4*)(obase + (size_t)row * OUTW) = ov;
      }
    }
  }
}

// =====================================================================
// Fallback: fused kernel (used only if ws is too small). Reads z directly.
// =====================================================================
__global__ __launch_bounds__(256, 2) void fused_decoder_kernel(
    const float* __restrict__ zp, const float* __restrict__ wp,
    const float* __restrict__ gammap, const float* __restrict__ betap,
    const float* __restrict__ convwp, const float* __restrict__ convbp,
    float* __restrict__ out) {
  const int tid = threadIdx.x;
  const int g0  = blockIdx.x * 32;

  __shared__ ushort As[BATCH * BK];
  __shared__ ushort Bs[32 * BK];
  __shared__ float statS[2][2][16];
  __shared__ float statQ[2][2][16];

  const int lane = tid & 63;
  const int w    = tid >> 6;
  const int wm   = w & 1;
  const int wn   = w >> 1;
  const int q    = lane >> 4;
  const int cl   = lane & 15;

  f32x4 acc[4];
  const f32x4 vzero = {0.f, 0.f, 0.f, 0.f};
#pragma unroll
  for (int i = 0; i < 4; ++i) acc[i] = vzero;

  for (int it = 0; it < 32; ++it) {
    const int k0 = it * BK;
    __syncthreads();
#pragma unroll
    for (int i = 0; i < 4; ++i) {
      int c = i * 256 + tid;
      int r = c >> 3, sc = c & 7;
      int gk = k0 + sc * 8;
      int4 v = make_int4(0, 0, 0, 0);
      if (gk < LAT) v = pack8(zp + (size_t)r * LAT + gk);
      *(int4*)&As[r * BK + ((sc ^ (r & 7)) << 3)] = v;
    }
    {
      int r = tid >> 3, sc = tid & 7;
      int g  = g0 + r;
      int gk = k0 + sc * 8;
      int4 v = make_int4(0, 0, 0, 0);
      if (gk < LAT && g < NG) v = pack8(wp + (size_t)g * LAT + gk);
      *(int4*)&Bs[r * BK + ((sc ^ (r & 7)) << 3)] = v;
    }
    __syncthreads();
#pragma unroll
    for (int kk = 0; kk < 2; ++kk) {
      int sc = kk * 4 + q;
      bf16x8 af[4], bfr;
#pragma unroll
      for (int mt = 0; mt < 4; ++mt) {
        int ra = wm * 64 + mt * 16 + cl;
        af[mt] = *(const bf16x8*)&As[ra * BK + ((sc ^ (ra & 7)) << 3)];
      }
      {
        int rb = wn * 16 + cl;
        bfr = *(const bf16x8*)&Bs[rb * BK + ((sc ^ (rb & 7)) << 3)];
      }
#pragma unroll
      for (int mt = 0; mt < 4; ++mt)
        acc[mt] = __builtin_amdgcn_mfma_f32_16x16x32_bf16(af[mt], bfr,
                                                          acc[mt], 0, 0, 0);
    }
  }

  float s = 0.f, ss = 0.f;
#pragma unroll
  for (int mt = 0; mt < 4; ++mt)
#pragma unroll
    for (int r = 0; r < 4; ++r) {
      float v = acc[mt][r];
      s += v; ss += v * v;
    }
  s += __shfl_xor(s, 16); ss += __shfl_xor(ss, 16);
  s += __shfl_xor(s, 32); ss += __shfl_xor(ss, 32);
  if (q == 0) { statS[wm][wn][cl] = s; statQ[wm][wn][cl] = ss; }
  __syncthreads();

  const int gcol = g0 + wn * 16 + cl;
  const int gc   = (gcol < NG) ? gcol : (NG - 1);
  float S = statS[0][wn][cl] + statS[1][wn][cl];
  float Q = statQ[0][wn][cl] + statQ[1][wn][cl];
  float mean = S * (1.f / 128.f);
  float var  = Q * (1.f / 128.f) - mean * mean;
  var = (var < 0.f) ? 0.f : var;
  float inv = __builtin_amdgcn_rsqf(var + EPSV);
  float ga = gammap[gc], be = betap[gc], cb = convbp[gc];
  float wv[KW];
  {
    const float4* pw = (const float4*)(convwp + (size_t)gc * KW);
#pragma unroll
    for (int j = 0; j < 5; ++j) {
      float4 f = pw[j];
      wv[4 * j] = f.x; wv[4 * j + 1] = f.y;
      wv[4 * j + 2] = f.z; wv[4 * j + 3] = f.w;
    }
  }
  float scale = inv * ga;
  float shift = be - mean * scale;
  const bool ok = (gcol < NG);
#pragma unroll
  for (int mt = 0; mt < 4; ++mt) {
#pragma unroll
    for (int r = 0; r < 4; ++r) {
      float h = acc[mt][r] * scale + shift;
      h = fmaxf(h, h * 0.1f);
      int b = wm * 64 + mt * 16 + q * 4 + r;
      float4 ov[5];
#pragma unroll
      for (int j = 0; j < 5; ++j) {
        float y0 = h * wv[4 * j]     + cb;
        float y1 = h * wv[4 * j + 1] + cb;
        float y2 = h * wv[4 * j + 2] + cb;
        float y3 = h * wv[4 * j + 3] + cb;
        y0 = fmaxf(y0, y0 * 0.1f);
        y1 = fmaxf(y1, y1 * 0.1f);
        y2 = fmaxf(y2, y2 * 0.1f);
        y3 = fmaxf(y3, y3 * 0.1f);
        ov[j].x = __builtin_amdgcn_rcpf(1.f + exp2f(y0 * -1.44269504f));
        ov[j].y = __builtin_amdgcn_rcpf(1.f + exp2f(y1 * -1.44269504f));
        ov[j].z = __builtin_amdgcn_rcpf(1.f + exp2f(y2 * -1.44269504f));
        ov[j].w = __builtin_amdgcn_rcpf(1.f + exp2f(y3 * -1.44269504f));
      }
      if (ok) {
        float4* po = (float4*)(out + (size_t)b * OUTW + (size_t)gcol * KW);
#pragma unroll
        for (int j = 0; j < 5; ++j) po[j] = ov[j];
      }
    }
  }
}

extern "C" void kernel_launch(void* const* d_in, const int* in_sizes, int n_in,
                              void* d_out, int out_size, void* d_ws, size_t ws_size,
                              hipStream_t stream) {
  const float* z     = (const float*)d_in[0];
  const float* W     = (const float*)d_in[1];
  // d_in[2] = b_fc: unused — cancels under training-mode batchnorm
  const float* gamma = (const float*)d_in[3];
  const float* beta  = (const float*)d_in[4];
  const float* convw = (const float*)d_in[5];
  const float* convb = (const float*)d_in[6];
  float* out = (float*)d_out;

  const size_t hp_elems   = (size_t)KSPL * NG * BATCH;    // 10,240,000
  const size_t hp_bytes   = hp_elems * sizeof(float);     // ~41 MB
  const size_t zswz_bytes = (size_t)NKT * 1024 * 16;      // 512 KB
  const size_t need = hp_bytes + zswz_bytes;

  if (ws_size >= need) {
    float* hp   = (float*)d_ws;
    int4* zswz  = (int4*)((char*)d_ws + hp_bytes);

    zprep_kernel<<<NKT, 256, 0, stream>>>(z, zswz);
    dim3 g1((NG + GT - 1) / GT, KSPL);     // 157 x 8 = 1256 blocks
    gemm_splitk_kernel<<<g1, 256, 0, stream>>>(zswz, W, hp);
    bn_expand_kernel<<<NG / EG, 256, 0, stream>>>(hp, gamma, beta, convw,
                                                  convb, out);
  } else {
    fused_decoder_kernel<<<(NG + 31) / 32, 256, 0, stream>>>(
        z, W, gamma, beta, convw, convb, out);
  }
}

// Round 3
// 196.111 us; speedup vs baseline: 1.0956x; 1.0956x over previous
//
#include <hip/hip_runtime.h>
#include <hip/hip_bf16.h>
#include <stdint.h>

// Problem constants (all inputs & output are FP32 per the reference file)
#define BATCH 128
#define LAT   2000
#define NG    10000
#define KW    20
#define OUTW  (NG * KW)   // 200000
#define EPSV  1e-5f

#define BK    64
#define NKT   32            // 64-wide k-tiles in padded z (2048 = 32*64)

// ---- fused kernel: groups per block (NG = 625 * 16 exactly)
#define EG        16
#define HR_STRIDE 132   // LDS row stride (floats): 132%32=4 -> small bank alias

typedef __bf16 bf16x8 __attribute__((ext_vector_type(8)));
typedef float  f32x4  __attribute__((ext_vector_type(4)));

__device__ __forceinline__ ushort f2bf(float f) {
  uint32_t u = __builtin_bit_cast(uint32_t, f);
  u = (u + 0x7FFFu + ((u >> 16) & 1u)) >> 16;  // RNE
  return (ushort)u;
}

__device__ __forceinline__ int4 pack8(const float* p) {
  float4 f0 = *(const float4*)p;
  float4 f1 = *(const float4*)(p + 4);
  int4 v;
  v.x = (int)((uint32_t)f2bf(f0.x) | ((uint32_t)f2bf(f0.y) << 16));
  v.y = (int)((uint32_t)f2bf(f0.z) | ((uint32_t)f2bf(f0.w) << 16));
  v.z = (int)((uint32_t)f2bf(f1.x) | ((uint32_t)f2bf(f1.y) << 16));
  v.w = (int)((uint32_t)f2bf(f1.z) | ((uint32_t)f2bf(f1.w) << 16));
  return v;
}

// async 16B global -> LDS (linear dest = wave-uniform base + lane*16)
__device__ __forceinline__ void gload_lds16(const void* g, void* l) {
  __builtin_amdgcn_global_load_lds(
      (const __attribute__((address_space(1))) unsigned int*)g,
      (__attribute__((address_space(3))) unsigned int*)l, 16, 0, 0);
}

// =====================================================================
// Phase 0: z (128 x 2000 f32) -> bf16, zero-padded to K=2048, stored in
// the EXACT swizzled-LDS image order per 64-k-tile so the fused GEMM can
// stage it with plain 16B global_load_lds (linear dest, pre-swizzled src).
// Image: chunk c (16B) of tile kt: r=c>>3, j=c&7 holds
//        z[r][kt*64+(j^(r&7))*8 .. +8].
// =====================================================================
__global__ __launch_bounds__(256) void zprep_kernel(
    const float* __restrict__ zp, int4* __restrict__ zswz) {
  const int cg = blockIdx.x * 256 + threadIdx.x;   // 0..32767
  const int kt = cg >> 10;
  const int c  = cg & 1023;
  const int r  = c >> 3, j = c & 7;
  const int sc = j ^ (r & 7);
  const int k0 = kt * 64 + sc * 8;
  int4 v = make_int4(0, 0, 0, 0);
  if (k0 < LAT) v = pack8(zp + (size_t)r * LAT + k0);   // LAT%8==0: no straddle
  zswz[cg] = v;
}

// =====================================================================
// Fused pipeline: one block = 16 groups x ALL 128 batches. Batch fits in
// the block, so BN stats are block-private: GEMM (full K=2000, no split-K,
// no hp intermediate) -> h in LDS -> stats via shuffle reduce -> store-
// coalesced expand. 625 blocks, 256 threads (4 waves, each owns 32 batches).
// =====================================================================
__global__ __launch_bounds__(256, 4) void fused16_kernel(
    const int4* __restrict__ zswz, const float* __restrict__ wp,
    const float* __restrict__ gammap, const float* __restrict__ betap,
    const float* __restrict__ convwp, const float* __restrict__ convbp,
    float* __restrict__ out) {
  const int tid = threadIdx.x;
  const int g0  = blockIdx.x * EG;

  __shared__ __attribute__((aligned(16))) ushort Zs[BATCH * BK];  // 16 KB
  __shared__ __attribute__((aligned(16))) ushort Ws[EG * BK];     //  2 KB
  __shared__ float  h_raw[EG * HR_STRIDE];   // raw (pre-BN) h
  __shared__ float4 cw_s[EG * 5];            // conv_w window
  __shared__ float  cb_s[EG];
  __shared__ float  scale_s[EG];
  __shared__ float  shift_s[EG];

  if (tid < EG * 5)
    cw_s[tid] = *(const float4*)(convwp + (size_t)g0 * KW + tid * 4);
  if (tid < EG) cb_s[tid] = convbp[g0 + tid];

  const int lane = tid & 63;
  const int w    = tid >> 6;     // wave id: batch offset w*32
  const int q    = lane >> 4;
  const int cl   = lane & 15;

  f32x4 acc[2];
  const f32x4 vzero = {0.f, 0.f, 0.f, 0.f};
  acc[0] = vzero; acc[1] = vzero;

  // ---- GEMM over full K (32 x 64-wide tiles, zero-padded to 2048) ----
  for (int it = 0; it < NKT; ++it) {
    __syncthreads();

    // stage z tile: 4 async 16B copies/thread from pre-swizzled image
    const int4* zt = zswz + (size_t)it * 1024;
#pragma unroll
    for (int i = 0; i < 4; ++i) {
      int c = i * 256 + tid;
      gload_lds16(zt + c, &Zs[c * 8]);
    }
    // stage W tile (16 rows x 64 k): 128 chunks, threads 0..127, 1 pack8 each
    if (tid < 128) {
      int r = tid >> 3, j = tid & 7;
      int gk = it * BK + j * 8;
      int4 v = make_int4(0, 0, 0, 0);
      if (gk < LAT) v = pack8(wp + (size_t)(g0 + r) * LAT + gk);
      *(int4*)&Ws[r * BK + ((j ^ (r & 7)) << 3)] = v;
    }
    __syncthreads();

#pragma unroll
    for (int kk = 0; kk < 2; ++kk) {
      int sc = kk * 4 + q;
      bf16x8 af = *(const bf16x8*)&Ws[cl * BK + ((sc ^ (cl & 7)) << 3)];
#pragma unroll
      for (int nt = 0; nt < 2; ++nt) {
        int rb = w * 32 + nt * 16 + cl;
        bf16x8 bfr = *(const bf16x8*)&Zs[rb * BK + ((sc ^ (rb & 7)) << 3)];
        acc[nt] = __builtin_amdgcn_mfma_f32_16x16x32_bf16(af, bfr, acc[nt],
                                                          0, 0, 0);
      }
    }
  }

  // ---- h -> LDS (D layout: row q*4+r = local group, col cl = batch) ----
#pragma unroll
  for (int nt = 0; nt < 2; ++nt)
#pragma unroll
    for (int r = 0; r < 4; ++r)
      h_raw[(q * 4 + r) * HR_STRIDE + w * 32 + nt * 16 + cl] = acc[nt][r];
  __syncthreads();

  // ---- BN stats: 512 (group,batch4) units over 256 threads x2 ----
  float sm[2], sq[2];
#pragma unroll
  for (int half = 0; half < 2; ++half) {
    const int idx = tid + half * 256;        // 0..511
    const int gl  = idx >> 5;                // local group 0..15
    const int bb  = (idx & 31) * 4;          // batch base 0..124
    const float4 a = *(const float4*)&h_raw[gl * HR_STRIDE + bb];
    sm[half] = a.x + a.y + a.z + a.w;
    sq[half] = a.x * a.x + a.y * a.y + a.z * a.z + a.w * a.w;
  }
  // 32 consecutive lanes share one group (aligned) -> masks stay in-group
#pragma unroll
  for (int m = 1; m < 32; m <<= 1) {
    sm[0] += __shfl_xor(sm[0], m); sq[0] += __shfl_xor(sq[0], m);
    sm[1] += __shfl_xor(sm[1], m); sq[1] += __shfl_xor(sq[1], m);
  }
  if ((tid & 31) == 0) {
#pragma unroll
    for (int half = 0; half < 2; ++half) {
      const int gl = (tid >> 5) + half * 8;
      float mean = sm[half] * (1.f / 128.f);
      float var  = sq[half] * (1.f / 128.f) - mean * mean;
      var = (var < 0.f) ? 0.f : var;
      float inv   = __builtin_amdgcn_rsqf(var + EPSV);
      float scale = inv * gammap[g0 + gl];
      scale_s[gl] = scale;
      shift_s[gl] = betap[g0 + gl] - mean * scale;
    }
  }
  __syncthreads();

  // ---- expansion: 240 threads = 3 batch rows x 80 float4 columns.
  // A wave's store covers 1024 contiguous output bytes. ----
  if (tid < 240) {
    const int col4 = tid % 80;           // float4 column in 1280-B window row
    const int r0   = tid / 80;           // 0..2
    const int gl   = col4 / 5;           // local group of this column
    const float4 w4  = cw_s[col4];
    const float  cb  = cb_s[gl];
    const float  scl = scale_s[gl];
    const float  sft = shift_s[gl];
    const float* hsrc = &h_raw[gl * HR_STRIDE];
    float* obase = out + (size_t)g0 * KW + (size_t)col4 * 4;
    for (int j = 0; j < 43; ++j) {       // ceil(128/3) passes
      const int row = j * 3 + r0;        // batch index
      if (row < BATCH) {
        float h = hsrc[row];
        h = fmaf(h, scl, sft);
        h = fmaxf(h, h * 0.1f);          // leaky(0.1)
        float y0 = fmaf(h, w4.x, cb);
        float y1 = fmaf(h, w4.y, cb);
        float y2 = fmaf(h, w4.z, cb);
        float y3 = fmaf(h, w4.w, cb);
        y0 = fmaxf(y0, y0 * 0.1f);
        y1 = fmaxf(y1, y1 * 0.1f);
        y2 = fmaxf(y2, y2 * 0.1f);
        y3 = fmaxf(y3, y3 * 0.1f);
        float4 ov;
        ov.x = __builtin_amdgcn_rcpf(1.f + exp2f(y0 * -1.44269504f));
        ov.y = __builtin_amdgcn_rcpf(1.f + exp2f(y1 * -1.44269504f));
        ov.z = __builtin_amdgcn_rcpf(1.f + exp2f(y2 * -1.44269504f));
        ov.w = __builtin_amdgcn_rcpf(1.f + exp2f(y3 * -1.44269504f));
        *(float4*)(obase + (size_t)row * OUTW) = ov;
      }
    }
  }
}

// =====================================================================
// Fallback: fused kernel (used only if ws is too small). Reads z directly.
// =====================================================================
__global__ __launch_bounds__(256, 2) void fused_decoder_kernel(
    const float* __restrict__ zp, const float* __restrict__ wp,
    const float* __restrict__ gammap, const float* __restrict__ betap,
    const float* __restrict__ convwp, const float* __restrict__ convbp,
    float* __restrict__ out) {
  const int tid = threadIdx.x;
  const int g0  = blockIdx.x * 32;

  __shared__ ushort As[BATCH * BK];
  __shared__ ushort Bs[32 * BK];
  __shared__ float statS[2][2][16];
  __shared__ float statQ[2][2][16];

  const int lane = tid & 63;
  const int w    = tid >> 6;
  const int wm   = w & 1;
  const int wn   = w >> 1;
  const int q    = lane >> 4;
  const int cl   = lane & 15;

  f32x4 acc[4];
  const f32x4 vzero = {0.f, 0.f, 0.f, 0.f};
#pragma unroll
  for (int i = 0; i < 4; ++i) acc[i] = vzero;

  for (int it = 0; it < 32; ++it) {
    const int k0 = it * BK;
    __syncthreads();
#pragma unroll
    for (int i = 0; i < 4; ++i) {
      int c = i * 256 + tid;
      int r = c >> 3, sc = c & 7;
      int gk = k0 + sc * 8;
      int4 v = make_int4(0, 0, 0, 0);
      if (gk < LAT) v = pack8(zp + (size_t)r * LAT + gk);
      *(int4*)&As[r * BK + ((sc ^ (r & 7)) << 3)] = v;
    }
    {
      int r = tid >> 3, sc = tid & 7;
      int g  = g0 + r;
      int gk = k0 + sc * 8;
      int4 v = make_int4(0, 0, 0, 0);
      if (gk < LAT && g < NG) v = pack8(wp + (size_t)g * LAT + gk);
      *(int4*)&Bs[r * BK + ((sc ^ (r & 7)) << 3)] = v;
    }
    __syncthreads();
#pragma unroll
    for (int kk = 0; kk < 2; ++kk) {
      int sc = kk * 4 + q;
      bf16x8 af[4], bfr;
#pragma unroll
      for (int mt = 0; mt < 4; ++mt) {
        int ra = wm * 64 + mt * 16 + cl;
        af[mt] = *(const bf16x8*)&As[ra * BK + ((sc ^ (ra & 7)) << 3)];
      }
      {
        int rb = wn * 16 + cl;
        bfr = *(const bf16x8*)&Bs[rb * BK + ((sc ^ (rb & 7)) << 3)];
      }
#pragma unroll
      for (int mt = 0; mt < 4; ++mt)
        acc[mt] = __builtin_amdgcn_mfma_f32_16x16x32_bf16(af[mt], bfr,
                                                          acc[mt], 0, 0, 0);
    }
  }

  float s = 0.f, ss = 0.f;
#pragma unroll
  for (int mt = 0; mt < 4; ++mt)
#pragma unroll
    for (int r = 0; r < 4; ++r) {
      float v = acc[mt][r];
      s += v; ss += v * v;
    }
  s += __shfl_xor(s, 16); ss += __shfl_xor(ss, 16);
  s += __shfl_xor(s, 32); ss += __shfl_xor(ss, 32);
  if (q == 0) { statS[wm][wn][cl] = s; statQ[wm][wn][cl] = ss; }
  __syncthreads();

  const int gcol = g0 + wn * 16 + cl;
  const int gc   = (gcol < NG) ? gcol : (NG - 1);
  float S = statS[0][wn][cl] + statS[1][wn][cl];
  float Q = statQ[0][wn][cl] + statQ[1][wn][cl];
  float mean = S * (1.f / 128.f);
  float var  = Q * (1.f / 128.f) - mean * mean;
  var = (var < 0.f) ? 0.f : var;
  float inv = __builtin_amdgcn_rsqf(var + EPSV);
  float ga = gammap[gc], be = betap[gc], cb = convbp[gc];
  float wv[KW];
  {
    const float4* pw = (const float4*)(convwp + (size_t)gc * KW);
#pragma unroll
    for (int j = 0; j < 5; ++j) {
      float4 f = pw[j];
      wv[4 * j] = f.x; wv[4 * j + 1] = f.y;
      wv[4 * j + 2] = f.z; wv[4 * j + 3] = f.w;
    }
  }
  float scale = inv * ga;
  float shift = be - mean * scale;
  const bool ok = (gcol < NG);
#pragma unroll
  for (int mt = 0; mt < 4; ++mt) {
#pragma unroll
    for (int r = 0; r < 4; ++r) {
      float h = acc[mt][r] * scale + shift;
      h = fmaxf(h, h * 0.1f);
      int b = wm * 64 + mt * 16 + q * 4 + r;
      float4 ov[5];
#pragma unroll
      for (int j = 0; j < 5; ++j) {
        float y0 = h * wv[4 * j]     + cb;
        float y1 = h * wv[4 * j + 1] + cb;
        float y2 = h * wv[4 * j + 2] + cb;
        float y3 = h * wv[4 * j + 3] + cb;
        y0 = fmaxf(y0, y0 * 0.1f);
        y1 = fmaxf(y1, y1 * 0.1f);
        y2 = fmaxf(y2, y2 * 0.1f);
        y3 = fmaxf(y3, y3 * 0.1f);
        ov[j].x = __builtin_amdgcn_rcpf(1.f + exp2f(y0 * -1.44269504f));
        ov[j].y = __builtin_amdgcn_rcpf(1.f + exp2f(y1 * -1.44269504f));
        ov[j].z = __builtin_amdgcn_rcpf(1.f + exp2f(y2 * -1.44269504f));
        ov[j].w = __builtin_amdgcn_rcpf(1.f + exp2f(y3 * -1.44269504f));
      }
      if (ok) {
        float4* po = (float4*)(out + (size_t)b * OUTW + (size_t)gcol * KW);
#pragma unroll
        for (int j = 0; j < 5; ++j) po[j] = ov[j];
      }
    }
  }
}

extern "C" void kernel_launch(void* const* d_in, const int* in_sizes, int n_in,
                              void* d_out, int out_size, void* d_ws, size_t ws_size,
                              hipStream_t stream) {
  const float* z     = (const float*)d_in[0];
  const float* W     = (const float*)d_in[1];
  // d_in[2] = b_fc: unused — cancels under training-mode batchnorm
  const float* gamma = (const float*)d_in[3];
  const float* beta  = (const float*)d_in[4];
  const float* convw = (const float*)d_in[5];
  const float* convb = (const float*)d_in[6];
  float* out = (float*)d_out;

  const size_t zswz_bytes = (size_t)NKT * 1024 * 16;      // 512 KB

  if (ws_size >= zswz_bytes) {
    int4* zswz = (int4*)d_ws;
    zprep_kernel<<<128, 256, 0, stream>>>(z, zswz);       // 32768 chunks
    fused16_kernel<<<NG / EG, 256, 0, stream>>>(zswz, W, gamma, beta,
                                                convw, convb, out);
  } else {
    fused_decoder_kernel<<<(NG + 31) / 32, 256, 0, stream>>>(
        z, W, gamma, beta, convw, convb, out);
  }
}